// Round 4
// baseline (35564.899 us; speedup 1.0000x reference)
//
#include <hip/hip_runtime.h>
#include <hip/hip_cooperative_groups.h>
#include <math.h>

namespace cg = cooperative_groups;

#define TSTEPS 512
#define BATCH  64
#define IDIM   128
#define HDIM   1024
#define JB     8              // output j-columns per block (register reuse)
#define NBLK   128            // blocks per layer; NBLK*JB == HDIM
#define NWAVE  16             // waves per block (1024 threads)
#define HKW    (HDIM / NWAVE) // recurrent k-slice per wave (64)
#define RSTR   72             // padded stride of reduction rows (2-way max)

// ws: 4 transposed state buffers [HDIM][BATCH] fp32:
//   buf0 ping/pong (layer 0), buf1 ping/pong (layer 1)
// Persistent cooperative kernel: blocks 0..127 = layer 0 (step i),
// blocks 128..255 = layer 1 (step i-1); grid.sync() per pipeline step.
__global__ __launch_bounds__(1024) void reservoir_kernel(
    const float* __restrict__ x,
    const float* __restrict__ Wi0, const float* __restrict__ Wh0,
    const float* __restrict__ Wi1, const float* __restrict__ Wh1,
    float* __restrict__ out, float* __restrict__ ws)
{
    cg::grid_group grid = cg::this_grid();

    __shared__ float red[NWAVE * JB * RSTR]; // 36.9 KB
    __shared__ float xs[IDIM * 65];          // 33.3 KB (layer-0 x, transposed)

    const int bid   = blockIdx.x;
    const int layer = (bid >= NBLK) ? 1 : 0;
    const int blk   = layer ? (bid - NBLK) : bid;
    const int tid   = (int)threadIdx.x;
    const int b     = tid & 63;
    const int wv    = __builtin_amdgcn_readfirstlane(tid >> 6);

    // zero the 4 state buffers: 4*1024*64 = 262144 floats = 256 blocks * 1024
    ws[(size_t)bid * 1024 + tid] = 0.0f;
    grid.sync();

    const float* __restrict__ Wh = (layer ? Wh1 : Wh0) + (size_t)(blk * JB) * HDIM;
    float* __restrict__ baseL = ws + (size_t)(2 * layer) * HDIM * BATCH;

    for (int i = 0; i <= TSTEPS; ++i) {
        const int t = layer ? (i - 1) : i;
        const bool valid = layer ? (t >= 0) : (t < TSTEPS);
        if (valid) {  // block-uniform branch: __syncthreads inside is safe
            const float* __restrict__ hR = baseL + (size_t)(t & 1) * HDIM * BATCH;
            float* __restrict__       hW = baseL + (size_t)((t + 1) & 1) * HDIM * BATCH;

            float acc[JB];
            #pragma unroll
            for (int jj = 0; jj < JB; ++jj) acc[jj] = 0.0f;

            if (layer == 0) {
                // stage x[t] (64x128, 32 KB) into LDS transposed, conflict-free
                const float* __restrict__ xsrc = x + (size_t)t * BATCH * IDIM;
                #pragma unroll
                for (int s = 0; s < 8; ++s) {
                    const int f = tid + s * 1024;           // coalesced read
                    xs[(f & 127) * 65 + (f >> 7)] = xsrc[f];
                }
                __syncthreads();
                const float* __restrict__ Wx = Wi0 + (size_t)(blk * JB) * IDIM;
                const int k0 = wv * (IDIM / NWAVE);         // 8 k per wave
                #pragma unroll
                for (int k = k0; k < k0 + IDIM / NWAVE; ++k) {
                    const float xv = xs[k * 65 + b];
                    #pragma unroll
                    for (int jj = 0; jj < JB; ++jj)
                        acc[jj] = fmaf(xv, Wx[(size_t)jj * IDIM + k], acc[jj]);
                }
            } else {
                // layer-1 input: e0[t] lives in layer-0's buffer (t+1)&1, [k][b]
                const float* __restrict__ xT = ws + (size_t)((t + 1) & 1) * HDIM * BATCH;
                const float* __restrict__ Wx = Wi1 + (size_t)(blk * JB) * HDIM;
                const int k0 = wv * HKW;
                #pragma unroll 8
                for (int k = k0; k < k0 + HKW; ++k) {
                    const float xv = xT[(size_t)k * BATCH + b]; // coalesced
                    #pragma unroll
                    for (int jj = 0; jj < JB; ++jj)
                        acc[jj] = fmaf(xv, Wx[(size_t)jj * HDIM + k], acc[jj]);
                }
            }

            // recurrent part: wave wv covers k in [wv*64, (wv+1)*64)
            {
                const int k0 = wv * HKW;
                #pragma unroll 8
                for (int k = k0; k < k0 + HKW; ++k) {
                    const float hv = hR[(size_t)k * BATCH + b]; // coalesced
                    #pragma unroll
                    for (int jj = 0; jj < JB; ++jj)
                        acc[jj] = fmaf(hv, Wh[(size_t)jj * HDIM + k], acc[jj]);
                }
            }

            // cross-wave reduction
            #pragma unroll
            for (int jj = 0; jj < JB; ++jj)
                red[(wv * JB + jj) * RSTR + b] = acc[jj];
            __syncthreads();

            if (tid < 512) {
                const int b2  = tid >> 3;      // 8 consecutive lanes share b2
                const int jj2 = tid & 7;
                float s = 0.0f;
                #pragma unroll
                for (int w2 = 0; w2 < NWAVE; ++w2)
                    s += red[(w2 * JB + jj2) * RSTR + b2];  // 2-way max (free)
                const int j = blk * JB + jj2;
                const float hold = hR[(size_t)j * BATCH + b2];
                const float hnew = 0.5f * hold + 0.5f * tanhf(s);
                hW[(size_t)j * BATCH + b2] = hnew;
                out[((size_t)((size_t)t * BATCH + b2) * 2 + layer) * HDIM + j] = hnew;
            }
        }
        grid.sync();  // orders hW/e0 writes for the next pipeline step
    }
}

extern "C" void kernel_launch(void* const* d_in, const int* in_sizes, int n_in,
                              void* d_out, int out_size, void* d_ws, size_t ws_size,
                              hipStream_t stream) {
    const float* x    = (const float*)d_in[0];
    const float* Wi0  = (const float*)d_in[1];
    const float* Wh0  = (const float*)d_in[2];
    const float* Wi1  = (const float*)d_in[3];
    const float* Wh1  = (const float*)d_in[4];
    float* out = (float*)d_out;
    float* ws  = (float*)d_ws;

    void* args[] = {(void*)&x, (void*)&Wi0, (void*)&Wh0, (void*)&Wi1,
                    (void*)&Wh1, (void*)&out, (void*)&ws};
    hipLaunchCooperativeKernel((const void*)reservoir_kernel,
                               dim3(2 * NBLK), dim3(1024), args, 0, stream);
}

// Round 5
// 30022.717 us; speedup vs baseline: 1.1846x; 1.1846x over previous
//
#include <hip/hip_runtime.h>
#include <math.h>

#define TSTEPS 512
#define BATCH  64
#define IDIM   128
#define HDIM   1024
#define JB     8              // output j-columns per block (register reuse)
#define NBLK   128            // blocks per layer; NBLK*JB == HDIM
#define NWAVE  16             // waves per block (1024 threads)
#define HKW    (HDIM / NWAVE) // recurrent k-slice per wave (64)
#define RSTR   72             // padded stride of reduction rows
#define NBLOCKS (2 * NBLK)    // 256 total
#define CNT_OFF (4 * HDIM * BATCH)  // float offset of barrier counter in ws

// Hand-rolled grid barrier. Each block: release-fence (wb own L2 writes) ->
// arrive (device-scope atomicAdd on LLC counter) -> tight spin -> acquire-fence
// (invalidate L1 + stale L2 lines). All blocks fence before arriving, so
// counter==target implies all state writes are LLC-visible; acquire kills the
// reader's stale copies of the ping-pong buffers (reused every 2 steps).
__device__ inline void grid_barrier(unsigned* cnt, unsigned target) {
    __syncthreads();  // all block stores complete (per-wave vmcnt before s_barrier)
    if (threadIdx.x == 0) {
        __builtin_amdgcn_fence(__ATOMIC_RELEASE, "agent");
        __hip_atomic_fetch_add(cnt, 1u, __ATOMIC_RELAXED, __HIP_MEMORY_SCOPE_AGENT);
        while (__hip_atomic_load(cnt, __ATOMIC_RELAXED, __HIP_MEMORY_SCOPE_AGENT) < target)
            __builtin_amdgcn_s_sleep(1);
        __builtin_amdgcn_fence(__ATOMIC_ACQUIRE, "agent");
    }
    __syncthreads();
}

// ws: 4 transposed state buffers [HDIM][BATCH] fp32 (layer0 ping/pong, layer1
// ping/pong), then the barrier counter at CNT_OFF.
// Persistent kernel: blocks 0..127 = layer 0 (step i), 128..255 = layer 1
// (step i-1); custom grid barrier per pipeline step.
__global__ __launch_bounds__(1024) void reservoir_kernel(
    const float* __restrict__ x,
    const float* __restrict__ Wi0, const float* __restrict__ Wh0,
    const float* __restrict__ Wi1, const float* __restrict__ Wh1,
    float* __restrict__ out, float* __restrict__ ws)
{
    __shared__ float red[NWAVE * JB * RSTR]; // 36.9 KB
    __shared__ float xs[IDIM * 65];          // 33.3 KB (layer-0 x, transposed)

    unsigned* cnt = (unsigned*)(ws + CNT_OFF);

    const int bid   = blockIdx.x;
    const int layer = (bid >= NBLK) ? 1 : 0;
    const int blk   = layer ? (bid - NBLK) : bid;
    const int tid   = (int)threadIdx.x;
    const int b     = tid & 63;
    const int wv    = __builtin_amdgcn_readfirstlane(tid >> 6);

    // zero the 4 state buffers: 4*1024*64 = 262144 floats = 256 blocks * 1024
    ws[(size_t)bid * 1024 + tid] = 0.0f;
    grid_barrier(cnt, NBLOCKS);

    const float* __restrict__ Wh = (layer ? Wh1 : Wh0) + (size_t)(blk * JB) * HDIM;
    float* __restrict__ baseL = ws + (size_t)(2 * layer) * HDIM * BATCH;

    for (int i = 0; i <= TSTEPS; ++i) {
        const int t = layer ? (i - 1) : i;
        const bool valid = layer ? (t >= 0) : (t < TSTEPS);
        if (valid) {  // block-uniform branch: __syncthreads inside is safe
            const float* __restrict__ hR = baseL + (size_t)(t & 1) * HDIM * BATCH;
            float* __restrict__       hW = baseL + (size_t)((t + 1) & 1) * HDIM * BATCH;

            float acc[JB];
            #pragma unroll
            for (int jj = 0; jj < JB; ++jj) acc[jj] = 0.0f;

            if (layer == 0) {
                // stage x[t] (64x128, 32 KB) into LDS transposed, conflict-free
                const float* __restrict__ xsrc = x + (size_t)t * BATCH * IDIM;
                #pragma unroll
                for (int s = 0; s < 8; ++s) {
                    const int f = tid + s * 1024;           // coalesced read
                    xs[(f & 127) * 65 + (f >> 7)] = xsrc[f];
                }
                __syncthreads();
                const float* __restrict__ Wx = Wi0 + (size_t)(blk * JB) * IDIM;
                const int k0 = wv * (IDIM / NWAVE);         // 8 k per wave
                #pragma unroll
                for (int k = k0; k < k0 + IDIM / NWAVE; ++k) {
                    const float xv = xs[k * 65 + b];
                    #pragma unroll
                    for (int jj = 0; jj < JB; ++jj)
                        acc[jj] = fmaf(xv, Wx[(size_t)jj * IDIM + k], acc[jj]);
                }
            } else {
                // layer-1 input: e0[t] lives in layer-0's buffer (t+1)&1, [k][b]
                const float* __restrict__ xT = ws + (size_t)((t + 1) & 1) * HDIM * BATCH;
                const float* __restrict__ Wx = Wi1 + (size_t)(blk * JB) * HDIM;
                const int k0 = wv * HKW;
                #pragma unroll 8
                for (int k = k0; k < k0 + HKW; ++k) {
                    const float xv = xT[(size_t)k * BATCH + b]; // coalesced
                    #pragma unroll
                    for (int jj = 0; jj < JB; ++jj)
                        acc[jj] = fmaf(xv, Wx[(size_t)jj * HDIM + k], acc[jj]);
                }
            }

            // recurrent part: wave wv covers k in [wv*64, (wv+1)*64)
            {
                const int k0 = wv * HKW;
                #pragma unroll 8
                for (int k = k0; k < k0 + HKW; ++k) {
                    const float hv = hR[(size_t)k * BATCH + b]; // coalesced
                    #pragma unroll
                    for (int jj = 0; jj < JB; ++jj)
                        acc[jj] = fmaf(hv, Wh[(size_t)jj * HDIM + k], acc[jj]);
                }
            }

            // cross-wave reduction
            #pragma unroll
            for (int jj = 0; jj < JB; ++jj)
                red[(wv * JB + jj) * RSTR + b] = acc[jj];
            __syncthreads();

            if (tid < 512) {
                const int b2  = tid >> 3;      // 8 consecutive lanes share b2
                const int jj2 = tid & 7;
                float s = 0.0f;
                #pragma unroll
                for (int w2 = 0; w2 < NWAVE; ++w2)
                    s += red[(w2 * JB + jj2) * RSTR + b2];
                const int j = blk * JB + jj2;
                const float hold = hR[(size_t)j * BATCH + b2];
                const float hnew = 0.5f * hold + 0.5f * tanhf(s);
                hW[(size_t)j * BATCH + b2] = hnew;
                out[((size_t)((size_t)t * BATCH + b2) * 2 + layer) * HDIM + j] = hnew;
            }
        }
        if (i < TSTEPS)  // last iteration: end-of-kernel release covers it
            grid_barrier(cnt, (unsigned)NBLOCKS * (unsigned)(i + 2));
    }
}

extern "C" void kernel_launch(void* const* d_in, const int* in_sizes, int n_in,
                              void* d_out, int out_size, void* d_ws, size_t ws_size,
                              hipStream_t stream) {
    const float* x    = (const float*)d_in[0];
    const float* Wi0  = (const float*)d_in[1];
    const float* Wh0  = (const float*)d_in[2];
    const float* Wi1  = (const float*)d_in[3];
    const float* Wh1  = (const float*)d_in[4];
    float* out = (float*)d_out;
    float* ws  = (float*)d_ws;

    // counter must be 0 at kernel start on EVERY replay (harness poisons ws
    // once and never re-poisons; kernel leaves the counter nonzero).
    hipMemsetAsync(ws + CNT_OFF, 0, 64, stream);

    void* args[] = {(void*)&x, (void*)&Wi0, (void*)&Wh0, (void*)&Wi1,
                    (void*)&Wh1, (void*)&out, (void*)&ws};
    hipLaunchCooperativeKernel((const void*)reservoir_kernel,
                               dim3(NBLOCKS), dim3(1024), args, 0, stream);
}

// Round 6
// 12202.460 us; speedup vs baseline: 2.9146x; 2.4604x over previous
//
#include <hip/hip_runtime.h>
#include <math.h>

#define TSTEPS 512
#define BATCH  64
#define IDIM   128
#define HDIM   1024
#define JB     8              // output j-columns per block (register reuse)
#define NBLK   128            // blocks per layer; NBLK*JB == HDIM
#define NWAVE  16             // waves per block (1024 threads)
#define RSTR   72             // padded stride of reduction rows
#define NBLOCKS (2 * NBLK)    // 256 total
#define CNT_OFF (4 * HDIM * BATCH)  // float offset of barrier counter in ws

// ---------------------------------------------------------------------------
// Coherence design: the 1 MB ping-pong state region in ws is accessed ONLY
// with system-coherent (sc0 sc1) loads/stores -> data lives at the LLC, no
// L1/L2 copies ever exist, so cross-XCD visibility needs NO cache-maintenance
// (round 5's 256 wbl2 + 256 inv per step were 95% of runtime). __syncthreads
// drains vmcnt(0) (= sc1-store completion at the LLC) before the relaxed
// arrival atomic, so the barrier is fence-free. Weights/x/out are normally
// cached: read-only (never stale) or write-only (flushed at kernel end).
// ---------------------------------------------------------------------------

// 8 system-coherent streaming loads from state[k..k+7][b] (256 B row stride).
#define ISSUE8(P, d0,d1,d2,d3,d4,d5,d6,d7) \
    asm volatile( \
        "global_load_dword %0, %8, off sc0 sc1\n\t" \
        "global_load_dword %1, %8, off offset:256 sc0 sc1\n\t" \
        "global_load_dword %2, %8, off offset:512 sc0 sc1\n\t" \
        "global_load_dword %3, %8, off offset:768 sc0 sc1\n\t" \
        "global_load_dword %4, %8, off offset:1024 sc0 sc1\n\t" \
        "global_load_dword %5, %8, off offset:1280 sc0 sc1\n\t" \
        "global_load_dword %6, %8, off offset:1536 sc0 sc1\n\t" \
        "global_load_dword %7, %8, off offset:1792 sc0 sc1" \
        : "=&v"(d0),"=&v"(d1),"=&v"(d2),"=&v"(d3), \
          "=&v"(d4),"=&v"(d5),"=&v"(d6),"=&v"(d7) \
        : "v"(P))

// Counted wait + scheduling fence (rule #18: FMAs must not hoist past this).
#define VWAIT(N) do { \
    asm volatile("s_waitcnt vmcnt(" #N ")" ::: "memory"); \
    __builtin_amdgcn_sched_barrier(0); } while (0)

// acc[jj] += v[q] * w[jj*1024 + KOFF + q]  (w is wave-uniform -> s_load)
#define FMACHUNK(W, KOFF, v0,v1,v2,v3,v4,v5,v6,v7) do { \
    const float vv_[8] = {v0,v1,v2,v3,v4,v5,v6,v7}; \
    _Pragma("unroll") \
    for (int q_ = 0; q_ < 8; ++q_) { \
        _Pragma("unroll") \
        for (int jj_ = 0; jj_ < JB; ++jj_) \
            acc[jj_] = fmaf(vv_[q_], (W)[jj_ * 1024 + (KOFF) + q_], acc[jj_]); \
    } } while (0)

// 64-k dot-stream: state base &st[k0*64+b], weight base &W[row0][k0] (stride
// 1024). 8-load batches, 2-deep pipeline, counted vmcnt waits.
__device__ __forceinline__ void dot_stream64(
    const float* p, const float* w, float* __restrict__ acc)
{
    float a0,a1,a2,a3,a4,a5,a6,a7;
    float b0,b1,b2,b3,b4,b5,b6,b7;
    ISSUE8(p, a0,a1,a2,a3,a4,a5,a6,a7);
    #pragma unroll
    for (int c = 0; c < 8; c += 2) {
        ISSUE8(p + (c + 1) * 512, b0,b1,b2,b3,b4,b5,b6,b7);
        VWAIT(8);
        FMACHUNK(w, c * 8, a0,a1,a2,a3,a4,a5,a6,a7);
        if (c < 6) {
            ISSUE8(p + (c + 2) * 512, a0,a1,a2,a3,a4,a5,a6,a7);
            VWAIT(8);
        } else {
            VWAIT(0);
        }
        FMACHUNK(w, (c + 1) * 8, b0,b1,b2,b3,b4,b5,b6,b7);
    }
}

__device__ __forceinline__ float llc_load(const float* p) {
    return __hip_atomic_load(p, __ATOMIC_RELAXED, __HIP_MEMORY_SCOPE_AGENT);
}
__device__ __forceinline__ void llc_store(float* p, float v) {
    __hip_atomic_store(p, v, __ATOMIC_RELAXED, __HIP_MEMORY_SCOPE_AGENT);
}

// Fence-free grid barrier (see header comment for why this is sufficient).
__device__ inline void grid_barrier(unsigned* cnt, unsigned target) {
    __syncthreads();   // drains vmcnt(0): all block sc1 stores are at the LLC
    if (threadIdx.x == 0) {
        __hip_atomic_fetch_add(cnt, 1u, __ATOMIC_RELAXED, __HIP_MEMORY_SCOPE_AGENT);
        while (__hip_atomic_load(cnt, __ATOMIC_RELAXED, __HIP_MEMORY_SCOPE_AGENT) < target)
            __builtin_amdgcn_s_sleep(1);
    }
    __syncthreads();
}

// ws: 4 transposed state buffers [HDIM][BATCH] fp32 (layer0 ping/pong, layer1
// ping/pong) -- sc1-only region -- then the barrier counter at CNT_OFF.
// Persistent kernel: blocks 0..127 = layer 0 (step i), 128..255 = layer 1
// (step i-1); fence-free grid barrier per pipeline step.
__global__ __launch_bounds__(1024) void reservoir_kernel(
    const float* __restrict__ x,
    const float* __restrict__ Wi0, const float* __restrict__ Wh0,
    const float* __restrict__ Wi1, const float* __restrict__ Wh1,
    float* __restrict__ out, float* __restrict__ ws)
{
    __shared__ float red[NWAVE * JB * RSTR]; // 36.9 KB
    __shared__ float xs[IDIM * 65];          // 33.3 KB (layer-0 x, transposed)

    unsigned* cnt = (unsigned*)(ws + CNT_OFF);

    const int bid   = blockIdx.x;
    const int layer = (bid >= NBLK) ? 1 : 0;
    const int blk   = layer ? (bid - NBLK) : bid;
    const int tid   = (int)threadIdx.x;
    const int b     = tid & 63;
    const int wv    = __builtin_amdgcn_readfirstlane(tid >> 6);

    // zero the state region with sc1 stores (256 blocks * 1024 thr = 262144)
    llc_store(&ws[(size_t)bid * 1024 + tid], 0.0f);
    grid_barrier(cnt, NBLOCKS);

    const float* __restrict__ Wh = (layer ? Wh1 : Wh0) + (size_t)(blk * JB) * HDIM;
    float* __restrict__ baseL = ws + (size_t)(2 * layer) * HDIM * BATCH;
    const int k0 = wv * 64;   // this wave's 64-k slice of each 1024-k stream

    for (int i = 0; i <= TSTEPS; ++i) {
        const int t = layer ? (i - 1) : i;
        const bool valid = layer ? (t >= 0) : (t < TSTEPS);
        if (valid) {  // block-uniform branch: __syncthreads inside is safe
            const float* __restrict__ hR = baseL + (size_t)(t & 1) * HDIM * BATCH;
            float* __restrict__       hW = baseL + (size_t)((t + 1) & 1) * HDIM * BATCH;

            float acc[JB];
            #pragma unroll
            for (int jj = 0; jj < JB; ++jj) acc[jj] = 0.0f;

            if (layer == 0) {
                // stage x[t] (64x128, 32 KB) into LDS transposed (normal cached)
                const float* __restrict__ xsrc = x + (size_t)t * BATCH * IDIM;
                #pragma unroll
                for (int s = 0; s < 8; ++s) {
                    const int f = tid + s * 1024;           // coalesced read
                    xs[(f & 127) * 65 + (f >> 7)] = xsrc[f];
                }
                __syncthreads();   // also drains staging vmcnt before counting
                const float* __restrict__ Wx = Wi0 + (size_t)(blk * JB) * IDIM;
                const int kx = wv * (IDIM / NWAVE);         // 8 k per wave
                #pragma unroll
                for (int k = kx; k < kx + IDIM / NWAVE; ++k) {
                    const float xv = xs[k * 65 + b];
                    #pragma unroll
                    for (int jj = 0; jj < JB; ++jj)
                        acc[jj] = fmaf(xv, Wx[(size_t)jj * IDIM + k], acc[jj]);
                }
            } else {
                // layer-1 input: e0[t] = layer-0 buffer (t+1)&1, [k][b], sc1
                const float* __restrict__ e0 = ws + (size_t)((t + 1) & 1) * HDIM * BATCH;
                const float* __restrict__ Wx = Wi1 + (size_t)(blk * JB) * HDIM;
                dot_stream64(e0 + (size_t)k0 * BATCH + b, Wx + k0, acc);
            }

            // recurrent part (sc1 stream)
            dot_stream64(hR + (size_t)k0 * BATCH + b, Wh + k0, acc);

            // cross-wave reduction (LDS, conflict-free)
            #pragma unroll
            for (int jj = 0; jj < JB; ++jj)
                red[(wv * JB + jj) * RSTR + b] = acc[jj];
            __syncthreads();

            if (tid < 512) {
                const int b2  = tid >> 3;      // 8 consecutive lanes share b2
                const int jj2 = tid & 7;
                float s = 0.0f;
                #pragma unroll
                for (int w2 = 0; w2 < NWAVE; ++w2)
                    s += red[(w2 * JB + jj2) * RSTR + b2];
                const int j = blk * JB + jj2;
                const float hold = llc_load(&hR[(size_t)j * BATCH + b2]);
                const float hnew = 0.5f * hold + 0.5f * tanhf(s);
                llc_store(&hW[(size_t)j * BATCH + b2], hnew);
                out[((size_t)((size_t)t * BATCH + b2) * 2 + layer) * HDIM + j] = hnew;
            }
        }
        if (i < TSTEPS)  // last iteration: end-of-kernel release covers out
            grid_barrier(cnt, (unsigned)NBLOCKS * (unsigned)(i + 2));
    }
}

extern "C" void kernel_launch(void* const* d_in, const int* in_sizes, int n_in,
                              void* d_out, int out_size, void* d_ws, size_t ws_size,
                              hipStream_t stream) {
    const float* x    = (const float*)d_in[0];
    const float* Wi0  = (const float*)d_in[1];
    const float* Wh0  = (const float*)d_in[2];
    const float* Wi1  = (const float*)d_in[3];
    const float* Wh1  = (const float*)d_in[4];
    float* out = (float*)d_out;
    float* ws  = (float*)d_ws;

    // counter must be 0 at kernel start on EVERY replay
    hipMemsetAsync(ws + CNT_OFF, 0, 64, stream);

    void* args[] = {(void*)&x, (void*)&Wi0, (void*)&Wh0, (void*)&Wi1,
                    (void*)&Wh1, (void*)&out, (void*)&ws};
    hipLaunchCooperativeKernel((const void*)reservoir_kernel,
                               dim3(NBLOCKS), dim3(1024), args, 0, stream);
}